// Round 8
// baseline (287.659 us; speedup 1.0000x reference)
//
#include <hip/hip_runtime.h>
#include <math.h>

constexpr int kB = 8, kS = 1024, kD = 512, kH = 8, kHD = 64;
constexpr int kM = kB * kS; // 8192 rows

typedef __attribute__((ext_vector_type(8))) short s8v;    // 8 bf16 (A/B frag)
typedef __attribute__((ext_vector_type(4))) float f4v;    // C/D frag
typedef __attribute__((ext_vector_type(4))) unsigned short u4v;

__device__ __forceinline__ unsigned short f2bf(float f) {
    union { float f; unsigned int u; } c; c.f = f;
    unsigned int u = c.u + 0x7FFFu + ((c.u >> 16) & 1u);
    return (unsigned short)(u >> 16);
}

// async global->LDS, 16B per lane; LDS dest = wave-uniform base + lane*16
__device__ __forceinline__ void gl2lds(const unsigned short* g, unsigned short* l) {
    __builtin_amdgcn_global_load_lds(
        (const __attribute__((address_space(1))) unsigned int*)g,
        (__attribute__((address_space(3))) unsigned int*)l, 16, 0, 0);
}

// ---------------- prep: fp32->bf16 cvt (+ I folded into W1), Wo^T transpose,
//                  bo row append, AND mem softmax (triangle-trimmed loads) ----
__global__ __launch_bounds__(256) void prep_kernel(
    const float* __restrict__ X, const float* __restrict__ Wq,
    const float* __restrict__ Wk, const float* __restrict__ Wv,
    const float* __restrict__ Wo, const float* __restrict__ W1,
    const float* __restrict__ ren, const float* __restrict__ ts,
    const float* __restrict__ bo_g,
    unsigned short* __restrict__ Xbf, unsigned short* __restrict__ Wqkv,
    unsigned short* __restrict__ WoT, unsigned short* __restrict__ W1bf,
    unsigned short* __restrict__ mem)
{
    __shared__ float red[4];
    const int t = threadIdx.x;
    if (blockIdx.x < 5120) {
        const int idx = blockIdx.x * 256 + t;
        const float* src; unsigned short* dst; int off; bool isw1 = false;
        if (idx < 1048576)      { src = X;  dst = Xbf;           off = idx; }
        else if (idx < 1114112) { src = Wq; dst = Wqkv;          off = idx - 1048576; }
        else if (idx < 1179648) { src = Wk; dst = Wqkv + 262144; off = idx - 1114112; }
        else if (idx < 1245184) { src = Wv; dst = Wqkv + 524288; off = idx - 1179648; }
        else                    { src = W1; dst = W1bf;          off = idx - 1245184; isw1 = true; }
        float4 v = ((const float4*)src)[off];
        if (isw1) { // fold residual: W1' = I + W1
            const int e0 = off * 4;
            const int row = e0 >> 9, col0 = e0 & 511;
            if (row >= col0 && row < col0 + 4) ((float*)&v)[row - col0] += 1.0f;
        }
        u4v p;
        p[0] = f2bf(v.x); p[1] = f2bf(v.y); p[2] = f2bf(v.z); p[3] = f2bf(v.w);
        ((u4v*)dst)[off] = p;
        return;
    }
    if (blockIdx.x >= 13312) {
        const int bi2 = blockIdx.x - 13312;
        if (bi2 < 64) {
            __shared__ float T[64][65];
            const int tr = bi2 >> 3, tc = bi2 & 7;
            const int rr0 = t >> 4, cc0 = (t & 15) * 4;
#pragma unroll
            for (int i2 = 0; i2 < 4; ++i2) {
                const int r = i2 * 16 + rr0;
                const float4 v = *(const float4*)&Wo[(size_t)(tr * 64 + r) * 512 + tc * 64 + cc0];
                T[r][cc0] = v.x; T[r][cc0 + 1] = v.y; T[r][cc0 + 2] = v.z; T[r][cc0 + 3] = v.w;
            }
            __syncthreads();
#pragma unroll
            for (int i2 = 0; i2 < 4; ++i2) {
                const int r2 = i2 * 16 + rr0;
                u4v p;
                p[0] = f2bf(T[cc0][r2]);     p[1] = f2bf(T[cc0 + 1][r2]);
                p[2] = f2bf(T[cc0 + 2][r2]); p[3] = f2bf(T[cc0 + 3][r2]);
                *(u4v*)&WoT[(size_t)(tc * 64 + r2) * 512 + tr * 64 + cc0] = p;
            }
        } else {
            // row 512 of WoT_ext = bo (feeds bias column of Wcomb)
            WoT[262144 + t]       = f2bf(bo_g[t]);
            WoT[262144 + 256 + t] = f2bf(bo_g[t + 256]);
        }
        return;
    }
    // ---- mem softmax; loads skipped beyond the causal diagonal ----
    const int bi = blockIdx.x - 5120;
    const int i = bi & (kS - 1);
    const float* renr = ren + (size_t)bi * kS;
    const float* tsr  = ts  + (size_t)bi * kS;
    unsigned short* memr = mem + (size_t)bi * kS;
    const int j0 = t * 4;
    float p4[4] = {0.0f, 0.0f, 0.0f, 0.0f};
    float lsum = 0.0f;
    if (j0 <= i) {
        const float4 r4 = *(const float4*)(renr + j0);
        const float4 t4 = *(const float4*)(tsr + j0);
        float rv[4] = {r4.x, r4.y, r4.z, r4.w};
        float tv[4] = {t4.x, t4.y, t4.z, t4.w};
#pragma unroll
        for (int e = 0; e < 4; ++e) {
            const int j = j0 + e;
            float p = 0.0f;
            if (j <= i) {
                const float val = 0.30102999566f * __log2f(rv[e] + 1.0f) + __expf(-fabsf(tv[e]));
                p = __expf(val);
            }
            p4[e] = p;
            lsum += p;
        }
    }
#pragma unroll
    for (int d = 1; d < 64; d <<= 1) lsum += __shfl_xor(lsum, d);
    if ((t & 63) == 0) red[t >> 6] = lsum;
    __syncthreads();
    const float Z = red[0] + red[1] + red[2] + red[3];
    const float inv = 1.0f / Z;
    u4v pk;
#pragma unroll
    for (int e = 0; e < 4; ++e) pk[e] = f2bf(p4[e] * inv);
    *(u4v*)(memr + j0) = pk;
}

// ------- MFMA GEMM core: acc(128 x NT*32) = A @ B^T, K=512 -------
// Double-buffered LDS, ONE barrier per K-step (validated r6).
template <int NT>
__device__ __forceinline__ void mfma_core2(
    const unsigned short* __restrict__ A, const unsigned short* __restrict__ B,
    int M0, int N0, unsigned short* As, unsigned short* Bs, f4v (&acc)[4][NT])
{
    const int t = threadIdx.x, w = t >> 6, lane = t & 63;
    const int l16 = lane & 15, quad = lane >> 4;
    const int wm = (w & 1) * 64, wn = (w >> 1) * (NT * 16);
    constexpr int NB = NT / 2;
    constexpr int ABUF = 128 * 32;
    constexpr int BBUF = NT * 32 * 32;

    const unsigned short* gA[2]; unsigned short* lA[2];
#pragma unroll
    for (int i = 0; i < 2; ++i) {
        const int r0 = w * 32 + i * 16;
        const int r = r0 + (lane >> 2);
        const int c = (lane & 3) ^ ((r >> 1) & 3);
        gA[i] = A + (size_t)(M0 + r) * 512 + c * 8;
        lA[i] = As + r0 * 32;
    }
    const unsigned short* gB[NB]; unsigned short* lB[NB];
#pragma unroll
    for (int i = 0; i < NB; ++i) {
        const int r0 = w * (16 * NB) + i * 16;
        const int r = r0 + (lane >> 2);
        const int c = (lane & 3) ^ ((r >> 1) & 3);
        gB[i] = B + (size_t)(N0 + r) * 512 + c * 8;
        lB[i] = Bs + r0 * 32;
    }

    const f4v zero = {0.0f, 0.0f, 0.0f, 0.0f};
#pragma unroll
    for (int mt = 0; mt < 4; ++mt)
#pragma unroll
        for (int nt = 0; nt < NT; ++nt) acc[mt][nt] = zero;

    gl2lds(gA[0], lA[0]);
    gl2lds(gA[1], lA[1]);
#pragma unroll
    for (int i = 0; i < NB; ++i) gl2lds(gB[i], lB[i]);

#pragma unroll 1
    for (int k0 = 0; k0 < 512; k0 += 32) {
        const int cur = (k0 >> 5) & 1;
        __syncthreads();
        if (k0 + 32 < 512) {
            const int nb = cur ^ 1;
            gl2lds(gA[0] + k0 + 32, lA[0] + nb * ABUF);
            gl2lds(gA[1] + k0 + 32, lA[1] + nb * ABUF);
#pragma unroll
            for (int i = 0; i < NB; ++i) gl2lds(gB[i] + k0 + 32, lB[i] + nb * BBUF);
        }
        s8v af[4], bf_[NT];
#pragma unroll
        for (int mt = 0; mt < 4; ++mt) {
            const int r = wm + mt * 16 + l16;
            const int p = r * 4 + (quad ^ ((r >> 1) & 3));
            af[mt] = *(const s8v*)&As[cur * ABUF + p * 8];
        }
#pragma unroll
        for (int nt = 0; nt < NT; ++nt) {
            const int r = wn + nt * 16 + l16;
            const int p = r * 4 + (quad ^ ((r >> 1) & 3));
            bf_[nt] = *(const s8v*)&Bs[cur * BBUF + p * 8];
        }
#pragma unroll
        for (int mt = 0; mt < 4; ++mt)
#pragma unroll
            for (int nt = 0; nt < NT; ++nt)
                acc[mt][nt] = __builtin_amdgcn_mfma_f32_16x16x32_bf16(
                    af[mt], bf_[nt], acc[mt][nt], 0, 0, 0);
    }
}

// ---- fused QKV (+ Wcomb build) ----
__global__ __launch_bounds__(256) void qkv_mfma_kernel(
    const unsigned short* __restrict__ Xbf, const unsigned short* __restrict__ Wqkv,
    const float* __restrict__ bq, const float* __restrict__ bk, const float* __restrict__ bv,
    const unsigned short* __restrict__ W1bf, const unsigned short* __restrict__ WoT,
    const float* __restrict__ b1,
    unsigned short* __restrict__ qbf, unsigned short* __restrict__ kbf,
    unsigned short* __restrict__ vTbf,
    unsigned short* __restrict__ Wcomb, float* __restrict__ bcomb)
{
    __shared__ __align__(16) unsigned short As[2 * 128 * 32];
    __shared__ __align__(16) unsigned short Bs[2 * 128 * 32];
    const int y = blockIdx.y;
    const int t = threadIdx.x, w = t >> 6, lane = t & 63;
    const int l16 = lane & 15, quad = lane >> 4;

    if (y == 12) {
        if (blockIdx.x >= 36) return;
        f4v acc[4][2];
        const int M0 = (blockIdx.x / 9) * 128, N0 = (blockIdx.x % 9) * 64;
        mfma_core2<2>(W1bf, WoT, M0, N0, As, Bs, acc);
        const int wm = (w & 1) * 64, wn = (w >> 1) * 32;
#pragma unroll
        for (int nt = 0; nt < 2; ++nt) {
            const int qq = N0 + wn + nt * 16 + l16;
#pragma unroll
            for (int mt = 0; mt < 4; ++mt)
#pragma unroll
                for (int rr = 0; rr < 4; ++rr) {
                    const int m = M0 + wm + mt * 16 + quad * 4 + rr;
                    if (qq < 512)       Wcomb[(size_t)m * 512 + qq] = f2bf(acc[mt][nt][rr]);
                    else if (qq == 512) bcomb[m] = acc[mt][nt][rr] + b1[m];
                }
        }
        return;
    }

    f4v acc[4][4];
    const int wm = (w & 1) * 64, wn = (w >> 1) * 64;
    if (y < 8) {
        const int M0 = blockIdx.x * 128, N0 = y * 128;
        mfma_core2<4>(Xbf, Wqkv, M0, N0, As, Bs, acc);
        const int z = N0 >> 9; // 0:q 1:k
        const float* bias = (z == 0) ? bq : bk;
        unsigned short* out = (z == 0) ? qbf : kbf;
#pragma unroll
        for (int nt = 0; nt < 4; ++nt) {
            const int n512 = (N0 + wn + nt * 16 + l16) & 511;
            const int h = n512 >> 6, hd = n512 & 63;
            const float bv_ = bias[n512];
#pragma unroll
            for (int mt = 0; mt < 4; ++mt) {
#pragma unroll
                for (int rr = 0; rr < 4; ++rr) {
                    const int m = M0 + wm + mt * 16 + quad * 4 + rr;
                    const int b = m >> 10, s = m & (kS - 1);
                    out[(((size_t)b * kH + h) * kS + s) * kHD + hd] =
                        f2bf(acc[mt][nt][rr] + bv_);
                }
            }
        }
    } else {
        const int M0 = (y - 8) * 128, N0 = blockIdx.x * 128;
        mfma_core2<4>(Wqkv + (size_t)1024 * 512, Xbf, M0, N0, As, Bs, acc);
#pragma unroll
        for (int mt = 0; mt < 4; ++mt) {
#pragma unroll
            for (int rr = 0; rr < 4; ++rr) {
                const int vcol = M0 + wm + mt * 16 + quad * 4 + rr;
                const int h = vcol >> 6, hd = vcol & 63;
                const float bv_ = bv[vcol];
#pragma unroll
                for (int nt = 0; nt < 4; ++nt) {
                    const int sg = N0 + wn + nt * 16 + l16;
                    const int b = sg >> 10, s = sg & (kS - 1);
                    vTbf[(((size_t)b * kH + h) * kHD + hd) * kS + s] =
                        f2bf(acc[mt][nt][rr] + bv_);
                }
            }
        }
    }
}

// ---- fused final GEMM + LayerNorm: out = LN(aout@Wcomb^T + bcomb) ----
// 256 blocks x 512 threads. Tile 32 rows x FULL 512 cols (wave w owns cols
// w*64..+63) so LN row-stats reduce inside the block. Wcomb (0.5 MB) is
// L2-hot broadcast. LDS: As dbuf 4KB + Bs dbuf 64KB = 68KB -> 2 blocks/CU cap.
__global__ __launch_bounds__(512, 2) void gemm_ln_kernel(
    const unsigned short* __restrict__ Abf, const unsigned short* __restrict__ Wcomb,
    const float* __restrict__ bcomb, const float* __restrict__ g,
    const float* __restrict__ bb, float* __restrict__ out)
{
    __shared__ __align__(16) unsigned short As[2 * 32 * 32];    // 4 KB
    __shared__ __align__(16) unsigned short Bs[2 * 512 * 32];   // 64 KB
    constexpr int ABUF = 32 * 32, BBUF = 512 * 32;
    const int t = threadIdx.x, w = t >> 6, lane = t & 63;
    const int l16 = lane & 15, quad = lane >> 4;
    const int M0 = blockIdx.x * 32;

    const unsigned short* gB[4]; unsigned short* lB[4];
#pragma unroll
    for (int i = 0; i < 4; ++i) {
        const int r0 = w * 64 + i * 16;
        const int r = r0 + (lane >> 2);
        const int c = (lane & 3) ^ ((r >> 1) & 3);
        gB[i] = Wcomb + (size_t)r * 512 + c * 8;
        lB[i] = Bs + r0 * 32;
    }
    const unsigned short* gA = nullptr; unsigned short* lA = nullptr;
    if (w < 2) {
        const int r0 = w * 16;
        const int r = r0 + (lane >> 2);
        const int c = (lane & 3) ^ ((r >> 1) & 3);
        gA = Abf + (size_t)(M0 + r) * 512 + c * 8;
        lA = As + r0 * 32;
    }

    const f4v zero = {0.0f, 0.0f, 0.0f, 0.0f};
    f4v acc[2][4];
#pragma unroll
    for (int mt = 0; mt < 2; ++mt)
#pragma unroll
        for (int nt = 0; nt < 4; ++nt) acc[mt][nt] = zero;

    // prologue stage k=0 into buf0
#pragma unroll
    for (int i = 0; i < 4; ++i) gl2lds(gB[i], lB[i]);
    if (w < 2) gl2lds(gA, lA);

#pragma unroll 1
    for (int k0 = 0; k0 < 512; k0 += 32) {
        const int cur = (k0 >> 5) & 1;
        __syncthreads();
        if (k0 + 32 < 512) {
            const int nb = cur ^ 1;
#pragma unroll
            for (int i = 0; i < 4; ++i) gl2lds(gB[i] + k0 + 32, lB[i] + nb * BBUF);
            if (w < 2) gl2lds(gA + k0 + 32, lA + nb * ABUF);
        }
        s8v af[2], bf_[4];
#pragma unroll
        for (int mt = 0; mt < 2; ++mt) {
            const int r = mt * 16 + l16;
            const int p = r * 4 + (quad ^ ((r >> 1) & 3));
            af[mt] = *(const s8v*)&As[cur * ABUF + p * 8];
        }
#pragma unroll
        for (int nt = 0; nt < 4; ++nt) {
            const int r = w * 64 + nt * 16 + l16;
            const int p = r * 4 + (quad ^ ((r >> 1) & 3));
            bf_[nt] = *(const s8v*)&Bs[cur * BBUF + p * 8];
        }
#pragma unroll
        for (int mt = 0; mt < 2; ++mt)
#pragma unroll
            for (int nt = 0; nt < 4; ++nt)
                acc[mt][nt] = __builtin_amdgcn_mfma_f32_16x16x32_bf16(
                    af[mt], bf_[nt], acc[mt][nt], 0, 0, 0);
    }

    // ---- epilogue: bias, row stats (sum, sumsq), LN, store ----
    float bias[4], gg[4], bbv[4];
#pragma unroll
    for (int nt = 0; nt < 4; ++nt) {
        const int n = w * 64 + nt * 16 + l16;
        bias[nt] = bcomb[n]; gg[nt] = g[n]; bbv[nt] = bb[n];
    }
#pragma unroll
    for (int mt = 0; mt < 2; ++mt)
#pragma unroll
        for (int nt = 0; nt < 4; ++nt)
#pragma unroll
            for (int rr = 0; rr < 4; ++rr) acc[mt][nt][rr] += bias[nt];

    // red in Bs buf0 (reads of buf0 finished before last top barrier);
    // stats in As buf0.
    float2* red = (float2*)Bs;      // [8 waves][32 rows]
    float2* stats = (float2*)As;    // [32 rows]
#pragma unroll
    for (int mt = 0; mt < 2; ++mt)
#pragma unroll
        for (int rr = 0; rr < 4; ++rr) {
            float s = 0.0f, qq = 0.0f;
#pragma unroll
            for (int nt = 0; nt < 4; ++nt) {
                const float v = acc[mt][nt][rr];
                s += v; qq += v * v;
            }
            s += __shfl_xor(s, 1); qq += __shfl_xor(qq, 1);
            s += __shfl_xor(s, 2); qq += __shfl_xor(qq, 2);
            s += __shfl_xor(s, 4); qq += __shfl_xor(qq, 4);
            s += __shfl_xor(s, 8); qq += __shfl_xor(qq, 8);
            if (l16 == 0) red[w * 32 + mt * 16 + quad * 4 + rr] = make_float2(s, qq);
        }
    __syncthreads();
    if (t < 32) {
        float s = 0.0f, qq = 0.0f;
#pragma unroll
        for (int wv = 0; wv < 8; ++wv) {
            const float2 f2 = red[wv * 32 + t];
            s += f2.x; qq += f2.y;
        }
        const float mu = s * (1.0f / kD);
        const float var = qq * (1.0f / kD) - mu * mu;
        stats[t] = make_float2(mu, rsqrtf(var + 1e-5f));
    }
    __syncthreads();
#pragma unroll
    for (int mt = 0; mt < 2; ++mt)
#pragma unroll
        for (int rr = 0; rr < 4; ++rr) {
            const int row = mt * 16 + quad * 4 + rr;
            const float2 st = stats[row];
#pragma unroll
            for (int nt = 0; nt < 4; ++nt) {
                const int n = w * 64 + nt * 16 + l16;
                out[(size_t)(M0 + row) * kD + n] =
                    (acc[mt][nt][rr] - st.x) * st.y * gg[nt] + bbv[nt];
            }
        }
}

// ---------------- flash attention: paired q-tiles, KVBLK=128 ----------------
// Grid 8 x H x B = 512 blocks = exactly 2 blocks/CU, ALL co-resident -> one
// round of at most 8 barrier-iterations (per-iteration-latency law, r0/r5/r6).
// Block handles q-tiles (hi=15-qp, lo=qp); K/V staged once, shared.
// LDS = KV dbuf 64KB + P 16KB = 80KB exactly -> 2 blocks/CU.
#define KFRAG(tile, r, c) (*(const s8v*)&(tile)[(size_t)(r) * 64 + ((((c) ^ ((r) & 7))) << 3)])
#define VFRAG(tile, r, c) (*(const s8v*)&(tile)[(size_t)(r) * 128 + ((((c) ^ ((r) & 15))) << 3)])

__global__ __launch_bounds__(256, 2) void flash_attn_kernel(
    const unsigned short* __restrict__ q, const unsigned short* __restrict__ k,
    const unsigned short* __restrict__ vT, const unsigned short* __restrict__ mem,
    const float* __restrict__ l1, unsigned short* __restrict__ aout)
{
    const int qp = blockIdx.x;           // 0..7
    const int hi = 15 - qp, lo = qp;
    const int h = blockIdx.y, b = blockIdx.z;
    const int bh = b * kH + h;
    const int t = threadIdx.x;
    const int w = t >> 6, lane = t & 63;
    const int quad = lane >> 4, l16 = lane & 15;
    const float lam = l1[0];

    __shared__ __align__(16) unsigned short KV[2][2][64 * 128]; // 64 KB dbuf
    __shared__ __align__(16) unsigned short P_lds[4][16 * 128]; // 16 KB per-wave

    const int tbase[2] = {hi * 64, lo * 64};
    s8v qa[2][2];
    const unsigned short* mbase[2];
#pragma unroll
    for (int ti = 0; ti < 2; ++ti) {
        const unsigned short* qrow = q + ((size_t)bh * kS + tbase[ti] + w * 16 + l16) * kHD;
        qa[ti][0] = *(const s8v*)(qrow + quad * 8);
        qa[ti][1] = *(const s8v*)(qrow + 32 + quad * 8);
        mbase[ti] = mem + ((size_t)b * kS + tbase[ti] + w * 16 + l16) * kS;
    }

    const unsigned short* kb = k + (size_t)bh * kS * kHD;
    const unsigned short* vb = vT + (size_t)bh * kHD * kS;

    const int nkt   = (hi >> 1) + 1;     // K-tiles of 128 for hi (max 8)
    const int nktlo = (lo >> 1) + 1;     // for lo

    // staging: 32 segments (16 K + 16 V) over 4 waves, 8 gl2lds per wave
    const unsigned short* gsrc[8];
    int gstep[8];
    unsigned short* ldst[8];
#pragma unroll
    for (int u = 0; u < 8; ++u) {
        const int seg = w * 8 + u;
        if (seg < 16) {                  // K seg: rows seg*8..+7 of [128][64]
            const int s = seg;
            const int rloc = s * 8 + (lane >> 3);
            const int chunk = (lane & 7) ^ ((lane >> 3) & 7);
            gsrc[u] = kb + (size_t)rloc * kHD + chunk * 8;
            gstep[u] = 128 * kHD;
            ldst[u] = &KV[0][0][s * 512];
        } else {                         // V seg: d-rows s*4..+3 of [64][128]
            const int s = seg - 16;
            const int d = s * 4 + (lane >> 4);
            const int chunk = (lane & 15) ^ ((lane >> 4) & 3) ^ ((s & 3) << 2);
            gsrc[u] = vb + (size_t)d * kS + chunk * 8;
            gstep[u] = 128;
            ldst[u] = &KV[0][1][s * 512];
        }
    }

    // prologue: stage k-tile 0 into buffer 0
#pragma unroll
    for (int u = 0; u < 8; ++u) gl2lds(gsrc[u], ldst[u]);

    const f4v zero = {0.0f, 0.0f, 0.0f, 0.0f};
    f4v Oa[2][4], Om[2][4];
    float lr[2][4];
#pragma unroll
    for (int ti = 0; ti < 2; ++ti)
#pragma unroll
        for (int nt = 0; nt < 4; ++nt) {
            Oa[ti][nt] = zero; Om[ti][nt] = zero; lr[ti][nt] = 0.0f;
        }

    for (int kt = 0; kt < nkt; ++kt) {
        __syncthreads();                 // stage(kt) landed; prev-buf reads done
        const int cur = kt & 1;
        if (kt + 1 < nkt) {
            const int boff = ((kt + 1) & 1) * 16384;
#pragma unroll
            for (int u = 0; u < 8; ++u)
                gl2lds(gsrc[u] + (size_t)(kt + 1) * gstep[u], ldst[u] + boff);
        }
        const bool alo = (kt < nktlo);
        s8v ma0[4], ma1[4];
#pragma unroll
        for (int ks = 0; ks < 4; ++ks)
            ma0[ks] = *(const s8v*)(mbase[0] + kt * 128 + ks * 32 + quad * 8);
        if (alo) {
#pragma unroll
            for (int ks = 0; ks < 4; ++ks)
                ma1[ks] = *(const s8v*)(mbase[1] + kt * 128 + ks * 32 + quad * 8);
        }
        const unsigned short* Kc = &KV[cur][0][0];
        const unsigned short* Vc = &KV[cur][1][0];

        s8v pa0[4], pa1[4];
        // hi tile: QK^T -> p -> P_lds -> pa0
        {
            const bool diag = (kt == nkt - 1);
#pragma unroll
            for (int ct = 0; ct < 8; ++ct) {
                const int r = ct * 16 + l16;
                const s8v kb0 = KFRAG(Kc, r, quad);
                const s8v kb1 = KFRAG(Kc, r, 4 + quad);
                f4v acc = zero;
                acc = __builtin_amdgcn_mfma_f32_16x16x32_bf16(qa[0][0], kb0, acc, 0, 0, 0);
                acc = __builtin_amdgcn_mfma_f32_16x16x32_bf16(qa[0][1], kb1, acc, 0, 0, 0);
#pragma unroll
                for (int rr = 0; rr < 4; ++rr) {
                    float p = __expf(acc[rr] * 0.125f);
                    if (diag && (kt * 128 + r) > (tbase[0] + w * 16 + quad * 4 + rr)) p = 0.0f;
                    lr[0][rr] += p;
                    const int pr = quad * 4 + rr;
                    const int ck = ct * 2 + (l16 >> 3);
                    P_lds[w][pr * 128 + (((ck ^ pr) & 15) << 3) + (l16 & 7)] = f2bf(p);
                }
            }
#pragma unroll
            for (int ks = 0; ks < 4; ++ks)
                pa0[ks] = *(const s8v*)&P_lds[w][l16 * 128 + ((((ks * 4 + quad) ^ l16) & 15) << 3)];
        }
        // lo tile (reuses P_lds[w] after pa0 is in regs)
        if (alo) {
            const bool diag = (kt == nktlo - 1);
#pragma unroll
            for (int ct = 0; ct < 8; ++ct) {
                const int r = ct * 16 + l16;
                const s8v kb0 = KFRAG(Kc, r, quad);
                const s8v kb1 = KFRAG(Kc, r, 4 + quad);
                f4v acc = zero;
                acc = __builtin_amdgcn_mfma_f32_16x16x32_bf16(qa[1][0], kb0, acc, 0, 0, 0);
                acc = __builtin_amdgcn_mfma_f32_16x16x32_bf16(qa[1][1], kb1, acc, 0, 0, 0);
#pragma unroll
                for (int rr = 0; rr < 4; ++rr) {
                    float p = __expf(acc[rr] * 0.125f);
                    if (diag && (kt * 128 + r) > (tbase[1] + w * 16 + quad * 4 + rr)) p = 0.0f;
                    lr[1][rr] += p;
                    const int pr = quad * 4 + rr;
                    const int ck = ct * 2 + (l16 >> 3);
                    P_lds[w][pr * 128 + (((ck ^ pr) & 15) << 3) + (l16 & 7)] = f2bf(p);
                }
            }
#pragma unroll
            for (int ks = 0; ks < 4; ++ks)
                pa1[ks] = *(const s8v*)&P_lds[w][l16 * 128 + ((((ks * 4 + quad) ^ l16) & 15) << 3)];
        }

        // PV: V fragments read once, feed all accumulator streams
#pragma unroll
        for (int nt = 0; nt < 4; ++nt) {
#pragma unroll
            for (int ks = 0; ks < 4; ++ks) {
                const s8v vfk = VFRAG(Vc, nt * 16 + l16, ks * 4 + quad);
                Oa[0][nt] = __builtin_amdgcn_mfma_f32_16x16x32_bf16(pa0[ks], vfk, Oa[0][nt], 0, 0, 0);
                Om[0][nt] = __builtin_amdgcn_mfma_f32_16x16x32_bf16(ma0[ks], vfk, Om[0][nt], 0, 0, 0);
                if (alo) {
                    Oa[1][nt] = __builtin_amdgcn_mfma_f32_16x16x32_bf16(pa1[ks], vfk, Oa[1][nt], 0, 0, 0);
                    Om[1][nt] = __builtin_amdgcn_mfma_f32_16x16x32_bf16(ma1[ks], vfk, Om[1][nt], 0, 0, 0);
                }
            }
        }
    }

    // epilogue: normalize + blend, both tiles
#pragma unroll
    for (int ti = 0; ti < 2; ++ti) {
        float inv4[4];
#pragma unroll
        for (int rr = 0; rr < 4; ++rr) {
            float Z = lr[ti][rr];
            Z += __shfl_xor(Z, 1);
            Z += __shfl_xor(Z, 2);
            Z += __shfl_xor(Z, 4);
            Z += __shfl_xor(Z, 8);
            inv4[rr] = (1.0f - lam) / Z;
        }
        const int r0 = tbase[ti] + w * 16;
#pragma unroll
        for (int nt = 0; nt < 4; ++nt)
#pragma unroll
            for (int rr = 0; rr < 4; ++rr) {
                const int i = r0 + quad * 4 + rr;
                const int d = h * kHD + nt * 16 + l16;
                aout[((size_t)b * kS + i) * kD + d] =
                    f2bf(Oa[ti][nt][rr] * inv4[rr] + lam * Om[ti][nt][rr]);
            }
    }
}

extern "C" void kernel_launch(void* const* d_in, const int* in_sizes, int n_in,
                              void* d_out, int out_size, void* d_ws, size_t ws_size,
                              hipStream_t stream) {
    const float* X   = (const float*)d_in[1];   // 'inputs' feeds q,k,v (query unused)
    const float* ren = (const float*)d_in[2];
    const float* ts  = (const float*)d_in[3];
    const float* Wq = (const float*)d_in[5];  const float* bq = (const float*)d_in[6];
    const float* Wk = (const float*)d_in[7];  const float* bk = (const float*)d_in[8];
    const float* Wv = (const float*)d_in[9];  const float* bv = (const float*)d_in[10];
    const float* Wo = (const float*)d_in[11]; const float* bo = (const float*)d_in[12];
    const float* W1 = (const float*)d_in[13]; const float* b1 = (const float*)d_in[14];
    const float* lng = (const float*)d_in[15]; const float* lnb = (const float*)d_in[16];
    const float* l1 = (const float*)d_in[17];
    float* out = (float*)d_out;

    char* wsb = (char*)d_ws;
    unsigned short* Xbf    = (unsigned short*)(wsb);                  // 8 MB
    unsigned short* Wqkvbf = (unsigned short*)(wsb + (8u  << 20));    // 1.5 MB
    unsigned short* WoTbf  = (unsigned short*)(wsb + (10u << 20));    // 576x512 bf16 (0.57 MB)
    unsigned short* W1bf   = (unsigned short*)(wsb + (11u << 20));    // 0.5 MB
    unsigned short* qbf    = (unsigned short*)(wsb + (12u << 20));    // 8 MB
    unsigned short* kbf    = (unsigned short*)(wsb + (20u << 20));    // 8 MB
    unsigned short* vTbf   = (unsigned short*)(wsb + (28u << 20));    // 8 MB
    unsigned short* membf  = (unsigned short*)(wsb + (36u << 20));    // 16 MB
    unsigned short* aoutbf = (unsigned short*)(wsb + (52u << 20));    // 8 MB
    unsigned short* Wcombf = (unsigned short*)(wsb + (60u << 20));    // 0.5 MB
    float*          bcombf = (float*)        (wsb + (61u << 20));     // 2 KB

    prep_kernel<<<dim3(13377), 256, 0, stream>>>(
        X, Wq, Wk, Wv, Wo, W1, ren, ts, bo, Xbf, Wqkvbf, WoTbf, W1bf, membf);
    qkv_mfma_kernel<<<dim3(kM / 128, 13), 256, 0, stream>>>(
        Xbf, Wqkvbf, bq, bk, bv, W1bf, WoTbf, b1, qbf, kbf, vTbf, Wcombf, bcombf);
    flash_attn_kernel<<<dim3(8, kH, kB), 256, 0, stream>>>(
        qbf, kbf, vTbf, membf, l1, aoutbf);
    gemm_ln_kernel<<<dim3(kM / 32), 512, 0, stream>>>(
        aoutbf, Wcombf, bcombf, lng, lnb, out);
}

// Round 11
// 236.090 us; speedup vs baseline: 1.2184x; 1.2184x over previous
//
#include <hip/hip_runtime.h>
#include <math.h>

constexpr int kB = 8, kS = 1024, kD = 512, kH = 8, kHD = 64;
constexpr int kM = kB * kS; // 8192 rows

typedef __attribute__((ext_vector_type(8))) short s8v;    // 8 bf16 (A/B frag)
typedef __attribute__((ext_vector_type(4))) float f4v;    // C/D frag
typedef __attribute__((ext_vector_type(4))) unsigned short u4v;

__device__ __forceinline__ unsigned short f2bf(float f) {
    union { float f; unsigned int u; } c; c.f = f;
    unsigned int u = c.u + 0x7FFFu + ((c.u >> 16) & 1u);
    return (unsigned short)(u >> 16);
}

// async global->LDS, 16B per lane; LDS dest = wave-uniform base + lane*16
__device__ __forceinline__ void gl2lds(const unsigned short* g, unsigned short* l) {
    __builtin_amdgcn_global_load_lds(
        (const __attribute__((address_space(1))) unsigned int*)g,
        (__attribute__((address_space(3))) unsigned int*)l, 16, 0, 0);
}

// ---------------- prep: fp32->bf16 cvt (+ I folded into W1), Wo^T transpose,
//                  bo row append, AND mem softmax (triangle-trimmed loads) ----
__global__ __launch_bounds__(256) void prep_kernel(
    const float* __restrict__ X, const float* __restrict__ Wq,
    const float* __restrict__ Wk, const float* __restrict__ Wv,
    const float* __restrict__ Wo, const float* __restrict__ W1,
    const float* __restrict__ ren, const float* __restrict__ ts,
    const float* __restrict__ bo_g,
    unsigned short* __restrict__ Xbf, unsigned short* __restrict__ Wqkv,
    unsigned short* __restrict__ WoT, unsigned short* __restrict__ W1bf,
    unsigned short* __restrict__ mem)
{
    __shared__ float red[4];
    const int t = threadIdx.x;
    if (blockIdx.x < 5120) {
        const int idx = blockIdx.x * 256 + t;
        const float* src; unsigned short* dst; int off; bool isw1 = false;
        if (idx < 1048576)      { src = X;  dst = Xbf;           off = idx; }
        else if (idx < 1114112) { src = Wq; dst = Wqkv;          off = idx - 1048576; }
        else if (idx < 1179648) { src = Wk; dst = Wqkv + 262144; off = idx - 1114112; }
        else if (idx < 1245184) { src = Wv; dst = Wqkv + 524288; off = idx - 1179648; }
        else                    { src = W1; dst = W1bf;          off = idx - 1245184; isw1 = true; }
        float4 v = ((const float4*)src)[off];
        if (isw1) { // fold residual: W1' = I + W1
            const int e0 = off * 4;
            const int row = e0 >> 9, col0 = e0 & 511;
            if (row >= col0 && row < col0 + 4) ((float*)&v)[row - col0] += 1.0f;
        }
        u4v p;
        p[0] = f2bf(v.x); p[1] = f2bf(v.y); p[2] = f2bf(v.z); p[3] = f2bf(v.w);
        ((u4v*)dst)[off] = p;
        return;
    }
    if (blockIdx.x >= 13312) {
        const int bi2 = blockIdx.x - 13312;
        if (bi2 < 64) {
            __shared__ float T[64][65];
            const int tr = bi2 >> 3, tc = bi2 & 7;
            const int rr0 = t >> 4, cc0 = (t & 15) * 4;
#pragma unroll
            for (int i2 = 0; i2 < 4; ++i2) {
                const int r = i2 * 16 + rr0;
                const float4 v = *(const float4*)&Wo[(size_t)(tr * 64 + r) * 512 + tc * 64 + cc0];
                T[r][cc0] = v.x; T[r][cc0 + 1] = v.y; T[r][cc0 + 2] = v.z; T[r][cc0 + 3] = v.w;
            }
            __syncthreads();
#pragma unroll
            for (int i2 = 0; i2 < 4; ++i2) {
                const int r2 = i2 * 16 + rr0;
                u4v p;
                p[0] = f2bf(T[cc0][r2]);     p[1] = f2bf(T[cc0 + 1][r2]);
                p[2] = f2bf(T[cc0 + 2][r2]); p[3] = f2bf(T[cc0 + 3][r2]);
                *(u4v*)&WoT[(size_t)(tc * 64 + r2) * 512 + tr * 64 + cc0] = p;
            }
        } else {
            // row 512 of WoT_ext = bo (feeds bias column of Wcomb)
            WoT[262144 + t]       = f2bf(bo_g[t]);
            WoT[262144 + 256 + t] = f2bf(bo_g[t + 256]);
        }
        return;
    }
    // ---- mem softmax; loads skipped beyond the causal diagonal ----
    const int bi = blockIdx.x - 5120;
    const int i = bi & (kS - 1);
    const float* renr = ren + (size_t)bi * kS;
    const float* tsr  = ts  + (size_t)bi * kS;
    unsigned short* memr = mem + (size_t)bi * kS;
    const int j0 = t * 4;
    float p4[4] = {0.0f, 0.0f, 0.0f, 0.0f};
    float lsum = 0.0f;
    if (j0 <= i) {
        const float4 r4 = *(const float4*)(renr + j0);
        const float4 t4 = *(const float4*)(tsr + j0);
        float rv[4] = {r4.x, r4.y, r4.z, r4.w};
        float tv[4] = {t4.x, t4.y, t4.z, t4.w};
#pragma unroll
        for (int e = 0; e < 4; ++e) {
            const int j = j0 + e;
            float p = 0.0f;
            if (j <= i) {
                const float val = 0.30102999566f * __log2f(rv[e] + 1.0f) + __expf(-fabsf(tv[e]));
                p = __expf(val);
            }
            p4[e] = p;
            lsum += p;
        }
    }
#pragma unroll
    for (int d = 1; d < 64; d <<= 1) lsum += __shfl_xor(lsum, d);
    if ((t & 63) == 0) red[t >> 6] = lsum;
    __syncthreads();
    const float Z = red[0] + red[1] + red[2] + red[3];
    const float inv = 1.0f / Z;
    u4v pk;
#pragma unroll
    for (int e = 0; e < 4; ++e) pk[e] = f2bf(p4[e] * inv);
    *(u4v*)(memr + j0) = pk;
}

// ------- MFMA GEMM core: acc(128 x NT*32) = A @ B^T, K=512 -------
// Double-buffered LDS, ONE barrier per K-step (validated r6).
template <int NT>
__device__ __forceinline__ void mfma_core2(
    const unsigned short* __restrict__ A, const unsigned short* __restrict__ B,
    int M0, int N0, unsigned short* As, unsigned short* Bs, f4v (&acc)[4][NT])
{
    const int t = threadIdx.x, w = t >> 6, lane = t & 63;
    const int l16 = lane & 15, quad = lane >> 4;
    const int wm = (w & 1) * 64, wn = (w >> 1) * (NT * 16);
    constexpr int NB = NT / 2;
    constexpr int ABUF = 128 * 32;
    constexpr int BBUF = NT * 32 * 32;

    const unsigned short* gA[2]; unsigned short* lA[2];
#pragma unroll
    for (int i = 0; i < 2; ++i) {
        const int r0 = w * 32 + i * 16;
        const int r = r0 + (lane >> 2);
        const int c = (lane & 3) ^ ((r >> 1) & 3);
        gA[i] = A + (size_t)(M0 + r) * 512 + c * 8;
        lA[i] = As + r0 * 32;
    }
    const unsigned short* gB[NB]; unsigned short* lB[NB];
#pragma unroll
    for (int i = 0; i < NB; ++i) {
        const int r0 = w * (16 * NB) + i * 16;
        const int r = r0 + (lane >> 2);
        const int c = (lane & 3) ^ ((r >> 1) & 3);
        gB[i] = B + (size_t)(N0 + r) * 512 + c * 8;
        lB[i] = Bs + r0 * 32;
    }

    const f4v zero = {0.0f, 0.0f, 0.0f, 0.0f};
#pragma unroll
    for (int mt = 0; mt < 4; ++mt)
#pragma unroll
        for (int nt = 0; nt < NT; ++nt) acc[mt][nt] = zero;

    gl2lds(gA[0], lA[0]);
    gl2lds(gA[1], lA[1]);
#pragma unroll
    for (int i = 0; i < NB; ++i) gl2lds(gB[i], lB[i]);

#pragma unroll 1
    for (int k0 = 0; k0 < 512; k0 += 32) {
        const int cur = (k0 >> 5) & 1;
        __syncthreads();
        if (k0 + 32 < 512) {
            const int nb = cur ^ 1;
            gl2lds(gA[0] + k0 + 32, lA[0] + nb * ABUF);
            gl2lds(gA[1] + k0 + 32, lA[1] + nb * ABUF);
#pragma unroll
            for (int i = 0; i < NB; ++i) gl2lds(gB[i] + k0 + 32, lB[i] + nb * BBUF);
        }
        s8v af[4], bf_[NT];
#pragma unroll
        for (int mt = 0; mt < 4; ++mt) {
            const int r = wm + mt * 16 + l16;
            const int p = r * 4 + (quad ^ ((r >> 1) & 3));
            af[mt] = *(const s8v*)&As[cur * ABUF + p * 8];
        }
#pragma unroll
        for (int nt = 0; nt < NT; ++nt) {
            const int r = wn + nt * 16 + l16;
            const int p = r * 4 + (quad ^ ((r >> 1) & 3));
            bf_[nt] = *(const s8v*)&Bs[cur * BBUF + p * 8];
        }
#pragma unroll
        for (int mt = 0; mt < 4; ++mt)
#pragma unroll
            for (int nt = 0; nt < NT; ++nt)
                acc[mt][nt] = __builtin_amdgcn_mfma_f32_16x16x32_bf16(
                    af[mt], bf_[nt], acc[mt][nt], 0, 0, 0);
    }
}

// ---- fused QKV (+ Wcomb build) ----
__global__ __launch_bounds__(256) void qkv_mfma_kernel(
    const unsigned short* __restrict__ Xbf, const unsigned short* __restrict__ Wqkv,
    const float* __restrict__ bq, const float* __restrict__ bk, const float* __restrict__ bv,
    const unsigned short* __restrict__ W1bf, const unsigned short* __restrict__ WoT,
    const float* __restrict__ b1,
    unsigned short* __restrict__ qbf, unsigned short* __restrict__ kbf,
    unsigned short* __restrict__ vTbf,
    unsigned short* __restrict__ Wcomb, float* __restrict__ bcomb)
{
    __shared__ __align__(16) unsigned short As[2 * 128 * 32];
    __shared__ __align__(16) unsigned short Bs[2 * 128 * 32];
    const int y = blockIdx.y;
    const int t = threadIdx.x, w = t >> 6, lane = t & 63;
    const int l16 = lane & 15, quad = lane >> 4;

    if (y == 12) {
        if (blockIdx.x >= 36) return;
        f4v acc[4][2];
        const int M0 = (blockIdx.x / 9) * 128, N0 = (blockIdx.x % 9) * 64;
        mfma_core2<2>(W1bf, WoT, M0, N0, As, Bs, acc);
        const int wm = (w & 1) * 64, wn = (w >> 1) * 32;
#pragma unroll
        for (int nt = 0; nt < 2; ++nt) {
            const int qq = N0 + wn + nt * 16 + l16;
#pragma unroll
            for (int mt = 0; mt < 4; ++mt)
#pragma unroll
                for (int rr = 0; rr < 4; ++rr) {
                    const int m = M0 + wm + mt * 16 + quad * 4 + rr;
                    if (qq < 512)       Wcomb[(size_t)m * 512 + qq] = f2bf(acc[mt][nt][rr]);
                    else if (qq == 512) bcomb[m] = acc[mt][nt][rr] + b1[m];
                }
        }
        return;
    }

    f4v acc[4][4];
    const int wm = (w & 1) * 64, wn = (w >> 1) * 64;
    if (y < 8) {
        const int M0 = blockIdx.x * 128, N0 = y * 128;
        mfma_core2<4>(Xbf, Wqkv, M0, N0, As, Bs, acc);
        const int z = N0 >> 9; // 0:q 1:k
        const float* bias = (z == 0) ? bq : bk;
        unsigned short* out = (z == 0) ? qbf : kbf;
#pragma unroll
        for (int nt = 0; nt < 4; ++nt) {
            const int n512 = (N0 + wn + nt * 16 + l16) & 511;
            const int h = n512 >> 6, hd = n512 & 63;
            const float bv_ = bias[n512];
#pragma unroll
            for (int mt = 0; mt < 4; ++mt) {
#pragma unroll
                for (int rr = 0; rr < 4; ++rr) {
                    const int m = M0 + wm + mt * 16 + quad * 4 + rr;
                    const int b = m >> 10, s = m & (kS - 1);
                    out[(((size_t)b * kH + h) * kS + s) * kHD + hd] =
                        f2bf(acc[mt][nt][rr] + bv_);
                }
            }
        }
    } else {
        const int M0 = (y - 8) * 128, N0 = blockIdx.x * 128;
        mfma_core2<4>(Wqkv + (size_t)1024 * 512, Xbf, M0, N0, As, Bs, acc);
#pragma unroll
        for (int mt = 0; mt < 4; ++mt) {
#pragma unroll
            for (int rr = 0; rr < 4; ++rr) {
                const int vcol = M0 + wm + mt * 16 + quad * 4 + rr;
                const int h = vcol >> 6, hd = vcol & 63;
                const float bv_ = bv[vcol];
#pragma unroll
                for (int nt = 0; nt < 4; ++nt) {
                    const int sg = N0 + wn + nt * 16 + l16;
                    const int b = sg >> 10, s = sg & (kS - 1);
                    vTbf[(((size_t)b * kH + h) * kHD + hd) * kS + s] =
                        f2bf(acc[mt][nt][rr] + bv_);
                }
            }
        }
    }
}

// ---- fused final GEMM + LayerNorm: out = LN(aout@Wcomb^T + bcomb) ----
__global__ __launch_bounds__(512, 2) void gemm_ln_kernel(
    const unsigned short* __restrict__ Abf, const unsigned short* __restrict__ Wcomb,
    const float* __restrict__ bcomb, const float* __restrict__ g,
    const float* __restrict__ bb, float* __restrict__ out)
{
    __shared__ __align__(16) unsigned short As[2 * 32 * 32];    // 4 KB
    __shared__ __align__(16) unsigned short Bs[2 * 512 * 32];   // 64 KB
    constexpr int ABUF = 32 * 32, BBUF = 512 * 32;
    const int t = threadIdx.x, w = t >> 6, lane = t & 63;
    const int l16 = lane & 15, quad = lane >> 4;
    const int M0 = blockIdx.x * 32;

    const unsigned short* gB[4]; unsigned short* lB[4];
#pragma unroll
    for (int i = 0; i < 4; ++i) {
        const int r0 = w * 64 + i * 16;
        const int r = r0 + (lane >> 2);
        const int c = (lane & 3) ^ ((r >> 1) & 3);
        gB[i] = Wcomb + (size_t)r * 512 + c * 8;
        lB[i] = Bs + r0 * 32;
    }
    const unsigned short* gA = nullptr; unsigned short* lA = nullptr;
    if (w < 2) {
        const int r0 = w * 16;
        const int r = r0 + (lane >> 2);
        const int c = (lane & 3) ^ ((r >> 1) & 3);
        gA = Abf + (size_t)(M0 + r) * 512 + c * 8;
        lA = As + r0 * 32;
    }

    const f4v zero = {0.0f, 0.0f, 0.0f, 0.0f};
    f4v acc[2][4];
#pragma unroll
    for (int mt = 0; mt < 2; ++mt)
#pragma unroll
        for (int nt = 0; nt < 4; ++nt) acc[mt][nt] = zero;

    // prologue stage k=0 into buf0
#pragma unroll
    for (int i = 0; i < 4; ++i) gl2lds(gB[i], lB[i]);
    if (w < 2) gl2lds(gA, lA);

#pragma unroll 1
    for (int k0 = 0; k0 < 512; k0 += 32) {
        const int cur = (k0 >> 5) & 1;
        __syncthreads();
        if (k0 + 32 < 512) {
            const int nb = cur ^ 1;
#pragma unroll
            for (int i = 0; i < 4; ++i) gl2lds(gB[i] + k0 + 32, lB[i] + nb * BBUF);
            if (w < 2) gl2lds(gA + k0 + 32, lA + nb * ABUF);
        }
        s8v af[2], bf_[4];
#pragma unroll
        for (int mt = 0; mt < 2; ++mt) {
            const int r = mt * 16 + l16;
            const int p = r * 4 + (quad ^ ((r >> 1) & 3));
            af[mt] = *(const s8v*)&As[cur * ABUF + p * 8];
        }
#pragma unroll
        for (int nt = 0; nt < 4; ++nt) {
            const int r = w * 64 + nt * 16 + l16;
            const int p = r * 4 + (quad ^ ((r >> 1) & 3));
            bf_[nt] = *(const s8v*)&Bs[cur * BBUF + p * 8];
        }
#pragma unroll
        for (int mt = 0; mt < 2; ++mt)
#pragma unroll
            for (int nt = 0; nt < 4; ++nt)
                acc[mt][nt] = __builtin_amdgcn_mfma_f32_16x16x32_bf16(
                    af[mt], bf_[nt], acc[mt][nt], 0, 0, 0);
    }

    // ---- epilogue: bias, row stats (sum, sumsq), LN, store ----
    float bias[4], gg[4], bbv[4];
#pragma unroll
    for (int nt = 0; nt < 4; ++nt) {
        const int n = w * 64 + nt * 16 + l16;
        bias[nt] = bcomb[n]; gg[nt] = g[n]; bbv[nt] = bb[n];
    }
#pragma unroll
    for (int mt = 0; mt < 2; ++mt)
#pragma unroll
        for (int nt = 0; nt < 4; ++nt)
#pragma unroll
            for (int rr = 0; rr < 4; ++rr) acc[mt][nt][rr] += bias[nt];

    float2* red = (float2*)Bs;      // [8 waves][32 rows]
    float2* stats = (float2*)As;    // [32 rows]
#pragma unroll
    for (int mt = 0; mt < 2; ++mt)
#pragma unroll
        for (int rr = 0; rr < 4; ++rr) {
            float s = 0.0f, qq = 0.0f;
#pragma unroll
            for (int nt = 0; nt < 4; ++nt) {
                const float v = acc[mt][nt][rr];
                s += v; qq += v * v;
            }
            s += __shfl_xor(s, 1); qq += __shfl_xor(qq, 1);
            s += __shfl_xor(s, 2); qq += __shfl_xor(qq, 2);
            s += __shfl_xor(s, 4); qq += __shfl_xor(qq, 4);
            s += __shfl_xor(s, 8); qq += __shfl_xor(qq, 8);
            if (l16 == 0) red[w * 32 + mt * 16 + quad * 4 + rr] = make_float2(s, qq);
        }
    __syncthreads();
    if (t < 32) {
        float s = 0.0f, qq = 0.0f;
#pragma unroll
        for (int wv = 0; wv < 8; ++wv) {
            const float2 f2 = red[wv * 32 + t];
            s += f2.x; qq += f2.y;
        }
        const float mu = s * (1.0f / kD);
        const float var = qq * (1.0f / kD) - mu * mu;
        stats[t] = make_float2(mu, rsqrtf(var + 1e-5f));
    }
    __syncthreads();
#pragma unroll
    for (int mt = 0; mt < 2; ++mt)
#pragma unroll
        for (int rr = 0; rr < 4; ++rr) {
            const int row = mt * 16 + quad * 4 + rr;
            const float2 st = stats[row];
#pragma unroll
            for (int nt = 0; nt < 4; ++nt) {
                const int n = w * 64 + nt * 16 + l16;
                out[(size_t)(M0 + row) * kD + n] =
                    (acc[mt][nt][rr] - st.x) * st.y * gg[nt] + bbv[nt];
            }
        }
}

// ---------------- flash attention: KVBLK=128, one 64-row q-tile per block ----
// (r6-measured variant: <40 us.) Grid (bh=64, tile=16), qt = 15-blockIdx.y so
// big blocks dispatch first. LDS = KV dbuf 64KB + P 16KB = 80KB -> 2 blocks/CU.
// Single q-tile keeps live state ~100 VGPR (r8's paired version spilled).
#define KFRAG(tile, r, c) (*(const s8v*)&(tile)[(size_t)(r) * 64 + ((((c) ^ ((r) & 7))) << 3)])
#define VFRAG(tile, r, c) (*(const s8v*)&(tile)[(size_t)(r) * 128 + ((((c) ^ ((r) & 15))) << 3)])

__global__ __launch_bounds__(256, 2) void flash_attn_kernel(
    const unsigned short* __restrict__ q, const unsigned short* __restrict__ k,
    const unsigned short* __restrict__ vT, const unsigned short* __restrict__ mem,
    const float* __restrict__ l1, unsigned short* __restrict__ aout)
{
    const int bh = blockIdx.x;           // 0..63
    const int qt = 15 - blockIdx.y;      // big tiles dispatch first
    const int b = bh >> 3, h = bh & 7;
    const int t = threadIdx.x;
    const int w = t >> 6, lane = t & 63;
    const int quad = lane >> 4, l16 = lane & 15;
    const float lam = l1[0];

    __shared__ __align__(16) unsigned short KV[2][2][64 * 128]; // 64 KB: [buf][K/V]
    __shared__ __align__(16) unsigned short P_lds[4][16 * 128]; // 16 KB per-wave P

    const int qbase = qt * 64;
    const unsigned short* qrow = q + ((size_t)bh * kS + qbase + w * 16 + l16) * kHD;
    const s8v qa0 = *(const s8v*)(qrow + quad * 8);
    const s8v qa1 = *(const s8v*)(qrow + 32 + quad * 8);
    const unsigned short* mbase = mem + ((size_t)b * kS + qbase + w * 16 + l16) * kS;

    const unsigned short* kb = k + (size_t)bh * kS * kHD;
    const unsigned short* vb = vT + (size_t)bh * kHD * kS;

    const int nkt = (qt >> 1) + 1;       // k-tiles of 128 (max 8)

    // staging: 32 segments (16 K + 16 V) over 4 waves, 8 gl2lds per wave
    const unsigned short* gsrc[8];
    int gstep[8];
    unsigned short* ldst[8];
#pragma unroll
    for (int u = 0; u < 8; ++u) {
        const int seg = w * 8 + u;
        if (seg < 16) {                  // K seg: rows seg*8..+7 of [128][64]
            const int s = seg;
            const int rloc = s * 8 + (lane >> 3);
            const int chunk = (lane & 7) ^ ((lane >> 3) & 7);
            gsrc[u] = kb + (size_t)rloc * kHD + chunk * 8;
            gstep[u] = 128 * kHD;
            ldst[u] = &KV[0][0][s * 512];
        } else {                         // V seg: rows (d) s*4..+3 of [64][128]
            const int s = seg - 16;
            const int d = s * 4 + (lane >> 4);
            const int chunk = (lane & 15) ^ ((lane >> 4) & 3) ^ ((s & 3) << 2);
            gsrc[u] = vb + (size_t)d * kS + chunk * 8;
            gstep[u] = 128;
            ldst[u] = &KV[0][1][s * 512];
        }
    }

    // prologue: stage k-tile 0 into buffer 0
#pragma unroll
    for (int u = 0; u < 8; ++u) gl2lds(gsrc[u], ldst[u]);

    const f4v zero = {0.0f, 0.0f, 0.0f, 0.0f};
    f4v Oa[4], Om[4];
    float lr[4];
#pragma unroll
    for (int nt = 0; nt < 4; ++nt) { Oa[nt] = zero; Om[nt] = zero; lr[nt] = 0.0f; }

    for (int kt = 0; kt < nkt; ++kt) {
        __syncthreads();                 // stage(kt) landed; prev-buf reads done
        const int cur = kt & 1;
        if (kt + 1 < nkt) {
            const int boff = ((kt + 1) & 1) * 16384;
#pragma unroll
            for (int u = 0; u < 8; ++u)
                gl2lds(gsrc[u] + (size_t)(kt + 1) * gstep[u], ldst[u] + boff);
        }
        // mem fragments in MFMA-A layout: row l16, k = kt*128 + ks*32 + quad*8
        s8v ma[4];
#pragma unroll
        for (int ks = 0; ks < 4; ++ks)
            ma[ks] = *(const s8v*)(mbase + kt * 128 + ks * 32 + quad * 8);

        const unsigned short* Kc = &KV[cur][0][0];
        const unsigned short* Vc = &KV[cur][1][0];
        const bool last = (kt == nkt - 1);

        // QK^T over 128 k-positions -> p = exp(s/8), masked -> 0
#pragma unroll
        for (int ct = 0; ct < 8; ++ct) {
            const int r = ct * 16 + l16;                 // k-pos in tile
            const s8v kb0 = KFRAG(Kc, r, quad);
            const s8v kb1 = KFRAG(Kc, r, 4 + quad);
            f4v acc = zero;
            acc = __builtin_amdgcn_mfma_f32_16x16x32_bf16(qa0, kb0, acc, 0, 0, 0);
            acc = __builtin_amdgcn_mfma_f32_16x16x32_bf16(qa1, kb1, acc, 0, 0, 0);
#pragma unroll
            for (int rr = 0; rr < 4; ++rr) {
                float p = __expf(acc[rr] * 0.125f);
                if (last && (kt * 128 + r) > (qbase + w * 16 + quad * 4 + rr)) p = 0.0f;
                lr[rr] += p;
                const int pr = quad * 4 + rr;
                const int ck = ct * 2 + (l16 >> 3);      // k-chunk 0..15
                P_lds[w][pr * 128 + (((ck ^ pr) & 15) << 3) + (l16 & 7)] = f2bf(p);
            }
        }
        // P in A-layout: row l16, chunk ks*4+quad (XOR l16)
        s8v pa[4];
#pragma unroll
        for (int ks = 0; ks < 4; ++ks)
            pa[ks] = *(const s8v*)&P_lds[w][l16 * 128 + ((((ks * 4 + quad) ^ l16) & 15) << 3)];
#pragma unroll
        for (int nt = 0; nt < 4; ++nt) {
#pragma unroll
            for (int ks = 0; ks < 4; ++ks) {
                const s8v vfk = VFRAG(Vc, nt * 16 + l16, ks * 4 + quad);
                Oa[nt] = __builtin_amdgcn_mfma_f32_16x16x32_bf16(pa[ks], vfk, Oa[nt], 0, 0, 0);
                Om[nt] = __builtin_amdgcn_mfma_f32_16x16x32_bf16(ma[ks], vfk, Om[nt], 0, 0, 0);
            }
        }
    }

    // epilogue: normalize + blend
    float inv4[4];
#pragma unroll
    for (int rr = 0; rr < 4; ++rr) {
        float Z = lr[rr];
        Z += __shfl_xor(Z, 1);
        Z += __shfl_xor(Z, 2);
        Z += __shfl_xor(Z, 4);
        Z += __shfl_xor(Z, 8);
        inv4[rr] = (1.0f - lam) / Z;
    }
    const int r0 = qbase + w * 16;
#pragma unroll
    for (int nt = 0; nt < 4; ++nt)
#pragma unroll
        for (int rr = 0; rr < 4; ++rr) {
            const int i = r0 + quad * 4 + rr;
            const int d = h * kHD + nt * 16 + l16;
            aout[((size_t)b * kS + i) * kD + d] =
                f2bf(Oa[nt][rr] * inv4[rr] + lam * Om[nt][rr]);
        }
}

extern "C" void kernel_launch(void* const* d_in, const int* in_sizes, int n_in,
                              void* d_out, int out_size, void* d_ws, size_t ws_size,
                              hipStream_t stream) {
    const float* X   = (const float*)d_in[1];   // 'inputs' feeds q,k,v (query unused)
    const float* ren = (const float*)d_in[2];
    const float* ts  = (const float*)d_in[3];
    const float* Wq = (const float*)d_in[5];  const float* bq = (const float*)d_in[6];
    const float* Wk = (const float*)d_in[7];  const float* bk = (const float*)d_in[8];
    const float* Wv = (const float*)d_in[9];  const float* bv = (const float*)d_in[10];
    const float* Wo = (const float*)d_in[11]; const float* bo = (const float*)d_in[12];
    const float* W1 = (const float*)d_in[13]; const float* b1 = (const float*)d_in[14];
    const float* lng = (const float*)d_in[15]; const float* lnb = (const float*)d_in[16];
    const float* l1 = (const float*)d_in[17];
    float* out = (float*)d_out;

    char* wsb = (char*)d_ws;
    unsigned short* Xbf    = (unsigned short*)(wsb);                  // 8 MB
    unsigned short* Wqkvbf = (unsigned short*)(wsb + (8u  << 20));    // 1.5 MB
    unsigned short* WoTbf  = (unsigned short*)(wsb + (10u << 20));    // 576x512 bf16 (0.57 MB)
    unsigned short* W1bf   = (unsigned short*)(wsb + (11u << 20));    // 0.5 MB
    unsigned short* qbf    = (unsigned short*)(wsb + (12u << 20));    // 8 MB
    unsigned short* kbf    = (unsigned short*)(wsb + (20u << 20));    // 8 MB
    unsigned short* vTbf   = (unsigned short*)(wsb + (28u << 20));    // 8 MB
    unsigned short* membf  = (unsigned short*)(wsb + (36u << 20));    // 16 MB
    unsigned short* aoutbf = (unsigned short*)(wsb + (52u << 20));    // 8 MB
    unsigned short* Wcombf = (unsigned short*)(wsb + (60u << 20));    // 0.5 MB
    float*          bcombf = (float*)        (wsb + (61u << 20));     // 2 KB

    prep_kernel<<<dim3(13377), 256, 0, stream>>>(
        X, Wq, Wk, Wv, Wo, W1, ren, ts, bo, Xbf, Wqkvbf, WoTbf, W1bf, membf);
    qkv_mfma_kernel<<<dim3(kM / 128, 13), 256, 0, stream>>>(
        Xbf, Wqkvbf, bq, bk, bv, W1bf, WoTbf, b1, qbf, kbf, vTbf, Wcombf, bcombf);
    flash_attn_kernel<<<dim3(64, 16), 256, 0, stream>>>(
        qbf, kbf, vTbf, membf, l1, aoutbf);
    gemm_ln_kernel<<<dim3(kM / 32), 512, 0, stream>>>(
        aoutbf, Wcombf, bcombf, lng, lnb, out);
}